// Round 15
// baseline (745.169 us; speedup 1.0000x reference)
//
#include <hip/hip_runtime.h>
#include <math.h>

#define NB   8
#define NROI 400
#define GG   25
#define EMBD 360
#define HDD  90
#define TBM  1728
#define MTOK 13824      // NB*TBM

typedef __attribute__((ext_vector_type(8)))  _Float16 h8;   // 8 f16 (4 VGPR)
typedef __attribute__((ext_vector_type(4)))  _Float16 h4;
typedef __attribute__((ext_vector_type(16))) float f32x16;
typedef __attribute__((ext_vector_type(4)))  unsigned u32x4;

#define MFMA16(a,b,c) __builtin_amdgcn_mfma_f32_32x32x16_f16(a,b,c,0,0,0)
#define QSCALE 0.105409255338945984f   /* 1/sqrt(90) */

// direct global->LDS staging, 16B per lane; LDS dest = uniform base + lane*16
#define GLOAD_LDS(G, L) __builtin_amdgcn_global_load_lds( \
    (const __attribute__((address_space(1))) unsigned int*)(G), \
    (__attribute__((address_space(3))) unsigned int*)(L), 16, 0, 0)

__device__ __forceinline__ float gelu_f(float x) {
    return 0.5f * x * (1.0f + erff(x * 0.7071067811865475f));
}

// bijective XCD-aware block remap (m204): logical ids contiguous per XCD.
__device__ __forceinline__ int xcd_swz(int orig, int nwg) {
    int q = nwg >> 3, r = nwg & 7;
    int xcd = orig & 7, loc = orig >> 3;
    int base = (xcd < r) ? xcd * (q + 1) : r * (q + 1) + (xcd - r) * q;
    return base + loc;
}

// ---------------------------------------------------------------------------
// Tiled weight convert+transpose: W[K][N] fp32 -> Wt[Np][Kp] f16 (zero-pad).
// ---------------------------------------------------------------------------
__global__ __launch_bounds__(256) void k_wconv(
    const float* __restrict__ W, int K, int N,
    _Float16* __restrict__ Wt, int Kp, int Np, int Wls, int Wtls)
{
    W  += (size_t)blockIdx.z * Wls;
    Wt += (size_t)blockIdx.z * Wtls;
    __shared__ float tile[32][33];
    const int k0 = blockIdx.x * 32, n0 = blockIdx.y * 32;
    const int t = threadIdx.x;
    #pragma unroll
    for (int it = 0; it < 4; ++it) {
        int e = t + it * 256;
        int i = e >> 5, j = e & 31;
        tile[j][i] = (k0 + i < K && n0 + j < N) ? W[(size_t)(k0 + i) * N + n0 + j] : 0.0f;
    }
    __syncthreads();
    #pragma unroll
    for (int it = 0; it < 4; ++it) {
        int e = t + it * 256;
        int n = e >> 5, kk = e & 31;
        if (n0 + n < Np && k0 + kk < Kp)
            Wt[(size_t)(n0 + n) * Kp + k0 + kk] = (_Float16)tile[n][kk];
    }
}

// qkv(2x) + wo(2x) + qkv-bias(2x) conversions fused into one flat kernel.
__global__ __launch_bounds__(256) void k_wmisc(
    const float* __restrict__ wqkv, const float* __restrict__ wo,
    const float* __restrict__ bqkv,
    _Float16* __restrict__ qkvc, _Float16* __restrict__ woc,
    float* __restrict__ bqp)
{
    int id = blockIdx.x * 256 + threadIdx.x;
    if (id < 884736) {                       // qkv: Wt[1152][384], n' = sec*384+96h+d
        int l = id / 442368, r = id - l * 442368;
        int np = r / 384, kk = r - np * 384;
        int sec = np / 384, rr = np - sec * 384, h = rr / 96, d = rr - h * 96;
        float v = 0.0f;
        if (d < HDD && kk < 360) v = wqkv[(size_t)l * 388800 + (size_t)kk * 1080 + sec * 360 + h * HDD + d];
        if (sec == 0) v *= QSCALE;
        qkvc[id] = (_Float16)v;
    } else if (id < 1179648) {               // wo: Wt[384][384], k' = 96h+d
        int r2 = id - 884736;
        int l = r2 / 147456, r = r2 - l * 147456;
        int n = r / 384, kp = r - n * 384;
        int h = kp / 96, d = kp - h * 96;
        float v = 0.0f;
        if (d < HDD && n < 360) v = wo[(size_t)l * 129600 + (size_t)(h * HDD + d) * 360 + n];
        woc[r2] = (_Float16)v;
    } else if (id < 1181952) {               // padded qkv bias [1152]
        int r3 = id - 1179648;
        int l = r3 / 1152, r = r3 - l * 1152;
        int sec = r / 384, rr = r - sec * 384, h = rr / 96, d = rr - h * 96;
        float v = 0.0f;
        if (d < HDD) v = bqkv[l * 1080 + sec * 360 + h * HDD + d];
        if (sec == 0) v *= QSCALE;
        if (sec == 2 && d == HDD) v = 1.0f;  // softmax denominator column
        bqp[r3] = v;
    }
}

// ---------------------------------------------------------------------------
// V transpose: qkvh V-section [13824][96 per head] -> vT[bh][96][1728] f16.
// ---------------------------------------------------------------------------
__global__ __launch_bounds__(256) void k_vtr(
    const _Float16* __restrict__ qkvh, _Float16* __restrict__ vT)
{
    __shared__ _Float16 tile[32][33];
    const int t = threadIdx.x;
    const int tok0 = blockIdx.x * 32;
    const int d0 = blockIdx.y * 32;
    const int bh = blockIdx.z;              // b*4 + h
    const int b = bh >> 2, h = bh & 3;
    const size_t src = ((size_t)b * TBM + tok0) * 1152 + 768 + 96 * h + d0;
    #pragma unroll
    for (int it = 0; it < 4; ++it) {
        int tl = (t >> 5) + it * 8, dl = t & 31;
        tile[tl][dl] = qkvh[src + (size_t)tl * 1152 + dl];
    }
    __syncthreads();
    const size_t dst = ((size_t)bh * 96 + d0) * TBM + tok0;
    #pragma unroll
    for (int it = 0; it < 4; ++it) {
        int dl = (t >> 5) + it * 8, tl = t & 31;
        vT[dst + (size_t)dl * TBM + tl] = tile[tl][dl];
    }
}

// ---------------------------------------------------------------------------
// MFMA GEMM (f16): C = act(A@B + bias (+res)). 128x128 tile, BK=32, 4 waves.
// AH path: m97-style staging via global_load_lds (no VGPR round-trip);
// thread e stages LDS slot e (16B), source row = e&127, chunk c = e>>7.
// fp32-A path keeps register prefetch staging. XCD-swizzled block ids.
// ---------------------------------------------------------------------------
template <int ACT, bool RES, bool OUTH, bool AH, int MW>
__global__ __launch_bounds__(256, MW) void k_mgemm(
    const void* __restrict__ Ap, const _Float16* __restrict__ Bt,
    const float* __restrict__ bias, const float* res, void* Cp,
    int M, int N, int K, int Kp)
{
    __shared__ __align__(16) _Float16 Ah[4096], Bh[4096];
    const int t = threadIdx.x;
    const int lane = t & 63, wid = t >> 6;
    const int half = lane >> 5, l31 = lane & 31;
    const int nwg = gridDim.x * gridDim.y;
    const int logical = xcd_swz(blockIdx.y * gridDim.x + blockIdx.x, nwg);
    const int m0 = (logical / gridDim.x) * 128, n0 = (logical % gridDim.x) * 128;
    const int wm = (wid >> 1) * 64, wn = (wid & 1) * 64;
    const int wb = t & 192;          // wave-uniform base within 256

    f32x16 acc00 = {}, acc01 = {}, acc10 = {}, acc11 = {};
    const int nk = Kp >> 5;
    const bool k4 = (K & 3) == 0;

    const _Float16* Af = (const _Float16*)Ap;
    const float* A = (const float*)Ap;

    if (AH) {
        for (int ks = 0; ks < nk; ++ks) {
            const int k0 = ks << 5;
            __syncthreads();   // previous iteration's LDS readers done
            #pragma unroll
            for (int i = 0; i < 2; ++i) {
                int e = t + i * 256;
                int row = e & 127, c = e >> 7;
                GLOAD_LDS(Af + (size_t)(m0 + row) * Kp + k0 + c * 8,
                          &Ah[(i * 256 + wb) * 8]);
                GLOAD_LDS(Bt + (size_t)(n0 + row) * Kp + k0 + c * 8,
                          &Bh[(i * 256 + wb) * 8]);
            }
            __syncthreads();   // drains vmcnt before use
            h8 af[2][2], bf[2][2];
            #pragma unroll
            for (int m2 = 0; m2 < 2; ++m2)
                #pragma unroll
                for (int ku = 0; ku < 2; ++ku) {
                    int c = ku * 2 + half;
                    af[m2][ku] = *(const h8*)&Ah[(c * 128 + wm + m2 * 32 + l31) * 8];
                    bf[m2][ku] = *(const h8*)&Bh[(c * 128 + wn + m2 * 32 + l31) * 8];
                }
            #pragma unroll
            for (int ku = 0; ku < 2; ++ku) {
                acc00 = MFMA16(af[0][ku], bf[0][ku], acc00);
                acc01 = MFMA16(af[0][ku], bf[1][ku], acc01);
                acc10 = MFMA16(af[1][ku], bf[0][ku], acc10);
                acc11 = MFMA16(af[1][ku], bf[1][ku], acc11);
            }
        }
    } else {
        float4 fcur[4], fnxt[4];
        h8 bcur[2], bnxt[2];
        auto loadA_f = [&](int k0, float4* dst) {
            #pragma unroll
            for (int i = 0; i < 4; ++i) {
                int e = t + i * 256;
                int row = e >> 3, c4 = e & 7;
                int gm = m0 + row, kb = k0 + c4 * 4;
                float4 fv = {0.f, 0.f, 0.f, 0.f};
                if (gm < M) {
                    const float* ap = A + (size_t)gm * K + kb;
                    if (k4 && kb + 3 < K) {
                        fv = *(const float4*)ap;
                    } else {
                        if (kb + 0 < K) fv.x = ap[0];
                        if (kb + 1 < K) fv.y = ap[1];
                        if (kb + 2 < K) fv.z = ap[2];
                        if (kb + 3 < K) fv.w = ap[3];
                    }
                }
                dst[i] = fv;
            }
        };
        auto loadB = [&](int k0, h8* dst) {
            #pragma unroll
            for (int i = 0; i < 2; ++i) {
                int e = t + i * 256;
                int col = e >> 2, c = e & 3;
                dst[i] = *(const h8*)(Bt + (size_t)(n0 + col) * Kp + k0 + c * 8);
            }
        };
        loadA_f(0, fcur); loadB(0, bcur);
        for (int ks = 0; ks < nk; ++ks) {
            const bool pf = (ks + 1 < nk);
            if (pf) { loadA_f((ks + 1) << 5, fnxt); loadB((ks + 1) << 5, bnxt); }
            __syncthreads();
            #pragma unroll
            for (int i = 0; i < 4; ++i) {
                int e = t + i * 256;
                int row = e >> 3, c4 = e & 7;
                float4 fv = fcur[i];
                h4 hv = { (_Float16)fv.x, (_Float16)fv.y, (_Float16)fv.z, (_Float16)fv.w };
                int c = c4 >> 1, sub = c4 & 1;
                *(h4*)&Ah[(c * 128 + row) * 8 + sub * 4] = hv;
            }
            #pragma unroll
            for (int i = 0; i < 2; ++i) {
                int e = t + i * 256;
                int col = e >> 2, c = e & 3;
                *(h8*)&Bh[(c * 128 + col) * 8] = bcur[i];
            }
            __syncthreads();
            h8 af[2][2], bf[2][2];
            #pragma unroll
            for (int m2 = 0; m2 < 2; ++m2)
                #pragma unroll
                for (int ku = 0; ku < 2; ++ku) {
                    int c = ku * 2 + half;
                    af[m2][ku] = *(const h8*)&Ah[(c * 128 + wm + m2 * 32 + l31) * 8];
                    bf[m2][ku] = *(const h8*)&Bh[(c * 128 + wn + m2 * 32 + l31) * 8];
                }
            #pragma unroll
            for (int ku = 0; ku < 2; ++ku) {
                acc00 = MFMA16(af[0][ku], bf[0][ku], acc00);
                acc01 = MFMA16(af[0][ku], bf[1][ku], acc01);
                acc10 = MFMA16(af[1][ku], bf[0][ku], acc10);
                acc11 = MFMA16(af[1][ku], bf[1][ku], acc11);
            }
            if (pf) {
                fcur[0] = fnxt[0]; fcur[1] = fnxt[1]; fcur[2] = fnxt[2]; fcur[3] = fnxt[3];
                bcur[0] = bnxt[0]; bcur[1] = bnxt[1];
            }
        }
    }
    float* Cf = (float*)Cp;
    _Float16* Ch = (_Float16*)Cp;
    #define EPILOG(ACCV, M2, N2) { \
        int gn = n0 + wn + (N2) * 32 + l31; \
        if (gn < N) { \
            float bv = bias[gn]; \
            _Pragma("unroll") \
            for (int r = 0; r < 16; ++r) { \
                int gm = m0 + wm + (M2) * 32 + (r & 3) + 8 * (r >> 2) + 4 * half; \
                if (gm < M) { \
                    float v = ACCV[r] + bv; \
                    if (RES) v += res[(size_t)gm * N + gn]; \
                    if (ACT == 1) v = gelu_f(v); \
                    if (OUTH) Ch[(size_t)gm * N + gn] = (_Float16)v; \
                    else      Cf[(size_t)gm * N + gn] = v; \
                } } } }
    EPILOG(acc00, 0, 0) EPILOG(acc01, 0, 1) EPILOG(acc10, 1, 0) EPILOG(acc11, 1, 1)
    #undef EPILOG
}

// ---------------------------------------------------------------------------
// Split-K GEMM, global_load_lds staging, XCD swizzle: partial fp32 [MTOK][360].
// ---------------------------------------------------------------------------
__global__ __launch_bounds__(256, 4) void k_skgemm(
    const _Float16* __restrict__ A, const _Float16* __restrict__ Bt,
    float* __restrict__ P, int Kp, int KCH, int nstep)
{
    __shared__ __align__(16) _Float16 Ah[4096], Bh[4096];
    const int t = threadIdx.x;
    const int lane = t & 63, wid = t >> 6;
    const int half = lane >> 5, l31 = lane & 31;
    const int nwg = gridDim.x * gridDim.y;
    const int logical = xcd_swz(blockIdx.y * gridDim.x + blockIdx.x, nwg);
    const int m0 = (logical / gridDim.x) * 128, n0 = (logical % gridDim.x) * 128;
    const int wm = (wid >> 1) * 64, wn = (wid & 1) * 64;
    const int zb = blockIdx.z * KCH;
    const int wb = t & 192;
    P += (size_t)blockIdx.z * MTOK * EMBD;

    f32x16 acc00 = {}, acc01 = {}, acc10 = {}, acc11 = {};

    for (int ks = 0; ks < nstep; ++ks) {
        const int k0 = zb + (ks << 5);
        __syncthreads();
        #pragma unroll
        for (int i = 0; i < 2; ++i) {
            int e = t + i * 256;
            int row = e & 127, c = e >> 7;
            GLOAD_LDS(A + (size_t)(m0 + row) * Kp + k0 + c * 8,
                      &Ah[(i * 256 + wb) * 8]);
            GLOAD_LDS(Bt + (size_t)(n0 + row) * Kp + k0 + c * 8,
                      &Bh[(i * 256 + wb) * 8]);
        }
        __syncthreads();
        h8 af[2][2], bf[2][2];
        #pragma unroll
        for (int m2 = 0; m2 < 2; ++m2)
            #pragma unroll
            for (int ku = 0; ku < 2; ++ku) {
                int c = ku * 2 + half;
                af[m2][ku] = *(const h8*)&Ah[(c * 128 + wm + m2 * 32 + l31) * 8];
                bf[m2][ku] = *(const h8*)&Bh[(c * 128 + wn + m2 * 32 + l31) * 8];
            }
        #pragma unroll
        for (int ku = 0; ku < 2; ++ku) {
            acc00 = MFMA16(af[0][ku], bf[0][ku], acc00);
            acc01 = MFMA16(af[0][ku], bf[1][ku], acc01);
            acc10 = MFMA16(af[1][ku], bf[0][ku], acc10);
            acc11 = MFMA16(af[1][ku], bf[1][ku], acc11);
        }
    }
    #define EPILOGP(ACCV, M2, N2) { \
        int gn = n0 + wn + (N2) * 32 + l31; \
        if (gn < EMBD) { \
            _Pragma("unroll") \
            for (int r = 0; r < 16; ++r) { \
                int gm = m0 + wm + (M2) * 32 + (r & 3) + 8 * (r >> 2) + 4 * half; \
                P[(size_t)gm * EMBD + gn] = ACCV[r]; \
            } } }
    EPILOGP(acc00, 0, 0) EPILOGP(acc01, 0, 1) EPILOGP(acc10, 1, 0) EPILOGP(acc11, 1, 1)
    #undef EPILOGP
}

// ---------------------------------------------------------------------------
// Flash attention, f16 MFMA (T12 in-register softmax). Unchanged from R12.
// ---------------------------------------------------------------------------
__global__ __launch_bounds__(256, 2) void k_mattn(
    const _Float16* __restrict__ qkv, const _Float16* __restrict__ vT,
    _Float16* __restrict__ aob, const int* __restrict__ tcp)
{
    __shared__ __align__(16) _Float16 Kl[2][8192];   // [buf][kk*128 + chunk^ (kk&7)]
    __shared__ __align__(16) _Float16 Vl[2][6144];   // [buf][d*64 + (m^(d&7))*8]

    const int t = threadIdx.x;
    const int lane = t & 63, wid = t >> 6;
    const int half = lane >> 5, l31 = lane & 31;
    const int bid = blockIdx.x;
    const int bh = bid & 31, qt = bid >> 5;
    const int h = bh & 3, b = bh >> 2;
    const int Tc = *tcp;
    const int q0w = qt * 128 + wid * 32;
    const size_t base = (size_t)b * TBM * 1152 + 96 * h;
    const _Float16* vTb = vT + (size_t)bh * 96 * TBM;

    int skk[3], scc[3], sdd[3], smm[3];
    int koff[3], voff[3];
    #pragma unroll
    for (int i = 0; i < 3; ++i) {
        int cid = t + i * 256;
        skk[i] = cid / 12; scc[i] = cid - skk[i] * 12;
        sdd[i] = cid >> 3; smm[i] = cid & 7;
        koff[i] = skk[i] * 128 + ((scc[i] ^ (skk[i] & 7)) << 3);
        voff[i] = sdd[i] * 64 + ((smm[i] ^ (sdd[i] & 7)) << 3);
    }

    h8 qf[6];
    {
        int rl = q0w + l31; if (rl > TBM - 1) rl = TBM - 1;
        const _Float16* qrow = qkv + base + (size_t)rl * 1152;
        #pragma unroll
        for (int ku = 0; ku < 6; ++ku)
            qf[ku] = *(const h8*)(qrow + ku * 16 + half * 8);
    }

    f32x16 o0 = {}, o1 = {}, o2 = {};
    int nkt = (Tc + 63) >> 6; if (nkt > 27) nkt = 27;

    if (nkt > 0) {
        #pragma unroll
        for (int i = 0; i < 3; ++i) {
            *(h8*)&Kl[0][koff[i]] =
                *(const h8*)(qkv + base + (size_t)skk[i] * 1152 + 384 + scc[i] * 8);
            *(h8*)&Vl[0][voff[i]] =
                *(const h8*)(vTb + (size_t)sdd[i] * TBM + smm[i] * 8);
        }
    }
    __syncthreads();

    for (int kt = 0; kt < nkt; ++kt) {
        const int k0 = kt * 64;
        const int cur = kt & 1, nxt = cur ^ 1;
        h8 kpre[3], vpre[3];
        const bool pf = (kt + 1 < nkt);
        if (pf) {
            #pragma unroll
            for (int i = 0; i < 3; ++i) {
                kpre[i] = *(const h8*)(qkv + base + (size_t)(k0 + 64 + skk[i]) * 1152 + 384 + scc[i] * 8);
                vpre[i] = *(const h8*)(vTb + (size_t)sdd[i] * TBM + k0 + 64 + smm[i] * 8);
            }
        }
        // S^T = K Q (12 MFMAs)
        f32x16 sT0 = {}, sT1 = {};
        #pragma unroll
        for (int ku = 0; ku < 6; ++ku) {
            int c = ku * 2 + half;
            int cp = c ^ (l31 & 7);
            h8 kb0 = *(const h8*)&Kl[cur][l31 * 128 + cp * 8];
            h8 kb1 = *(const h8*)&Kl[cur][(32 + l31) * 128 + cp * 8];
            sT0 = MFMA16(kb0, qf[ku], sT0);
            sT1 = MFMA16(kb1, qf[ku], sT1);
        }
        // exp -> f16 pack -> permlane half-swap -> PV A-fragments (no LDS)
        h8 pa[4];
        #pragma unroll
        for (int g = 0; g < 2; ++g) {
            const f32x16& sT = g ? sT1 : sT0;
            const int kbase = k0 + g * 32;
            unsigned w0, w1, w2, w3, w4, w5, w6, w7;
            #define CVTW(W, R0, R1) { \
                int ka = kbase + ((R0) & 3) + 8 * ((R0) >> 2) + 4 * half; \
                int kb_ = kbase + ((R1) & 3) + 8 * ((R1) >> 2) + 4 * half; \
                float pva = (ka  < Tc) ? __expf(sT[R0]) : 0.0f; \
                float pvb = (kb_ < Tc) ? __expf(sT[R1]) : 0.0f; \
                W = __builtin_bit_cast(unsigned, __builtin_amdgcn_cvt_pkrtz(pva, pvb)); }
            CVTW(w0, 0, 1)  CVTW(w1, 2, 3)  CVTW(w2, 4, 5)  CVTW(w3, 6, 7)
            CVTW(w4, 8, 9)  CVTW(w5, 10, 11) CVTW(w6, 12, 13) CVTW(w7, 14, 15)
            #undef CVTW
            asm volatile("v_permlane32_swap_b32 %0, %1" : "+v"(w0), "+v"(w2));
            asm volatile("v_permlane32_swap_b32 %0, %1" : "+v"(w1), "+v"(w3));
            asm volatile("v_permlane32_swap_b32 %0, %1" : "+v"(w4), "+v"(w6));
            asm volatile("v_permlane32_swap_b32 %0, %1" : "+v"(w5), "+v"(w7));
            u32x4 lo = { w0, w1, w2, w3 };
            u32x4 hi = { w4, w5, w6, w7 };
            pa[g * 2 + 0] = __builtin_bit_cast(h8, lo);
            pa[g * 2 + 1] = __builtin_bit_cast(h8, hi);
        }
        // PV (12 MFMAs)
        #pragma unroll
        for (int n = 0; n < 3; ++n) {
            f32x16* op = n == 0 ? &o0 : (n == 1 ? &o1 : &o2);
            int d = n * 32 + l31;
            #pragma unroll
            for (int ku = 0; ku < 4; ++ku) {
                int m = ku * 2 + half;
                h8 vb = *(const h8*)&Vl[cur][d * 64 + ((m ^ (d & 7)) << 3)];
                *op = MFMA16(pa[ku], vb, *op);
            }
        }
        if (pf) {
            #pragma unroll
            for (int i = 0; i < 3; ++i) {
                *(h8*)&Kl[nxt][koff[i]] = kpre[i];
                *(h8*)&Vl[nxt][voff[i]] = vpre[i];
            }
        }
        __syncthreads();
    }

    #pragma unroll
    for (int r = 0; r < 16; ++r) {
        float den = __shfl(o2[r], (lane & 32) | 26);
        float inv = (den > 0.0f) ? 1.0f / den : 0.0f;
        int qg = q0w + (r & 3) + 8 * (r >> 2) + 4 * half;
        if (qg < Tc) {
            _Float16* orow = aob + ((size_t)b * TBM + qg) * 384 + 96 * h;
            orow[l31]      = (_Float16)(o0[r] * inv);
            orow[32 + l31] = (_Float16)(o1[r] * inv);
            orow[64 + l31] = (64 + l31 < HDD) ? (_Float16)(o2[r] * inv) : (_Float16)0.0f;
        }
    }
}

// ---------------------------------------------------------------------------
// Gather + 3^3 sum-pool + |.| mask accumulation (atomic)
// ---------------------------------------------------------------------------
__global__ __launch_bounds__(128) void k_pool(
    const float* __restrict__ F_emb, const int* __restrict__ C,
    float* __restrict__ nodes, float* __restrict__ vsum)
{
    const int tkn = blockIdx.x, b = blockIdx.y;
    const int oz = tkn % 12, oy = (tkn / 12) % 12, ox = tkn / 144;
    __shared__ int idx[27];
    const int tid = threadIdx.x;
    if (tid < 27) {
        int dx = tid / 9, dy = (tid / 3) % 3, dz = tid % 3;
        idx[tid] = C[(((b * GG) + ox * 2 + dx) * GG + oy * 2 + dy) * GG + oz * 2 + dz];
    }
    __syncthreads();
    float a0 = 0.f, a1 = 0.f, a2 = 0.f;
    for (int n = 0; n < 27; ++n) {
        int c = idx[n];
        if (c == 0) continue;
        const float* src = F_emb + (size_t)(b * NROI + (c - 1)) * EMBD;
        a0 += src[tid]; a1 += src[tid + 128];
        if (tid < 104) a2 += src[tid + 256];
    }
    float* dst = nodes + ((size_t)b * TBM + tkn) * EMBD;
    dst[tid] = a0; dst[tid + 128] = a1;
    if (tid < 104) dst[tid + 256] = a2;
    float s = fabsf(a0) + fabsf(a1) + ((tid < 104) ? fabsf(a2) : 0.0f);
    #pragma unroll
    for (int o = 32; o >= 1; o >>= 1) s += __shfl_xor(s, o);
    __shared__ float red[2];
    if ((tid & 63) == 0) red[tid >> 6] = s;
    __syncthreads();
    if (tid == 0) atomicAdd(&vsum[tkn], red[0] + red[1]);
}

__global__ __launch_bounds__(256) void k_scan(
    const float* __restrict__ vsum, int* __restrict__ cidx, int* __restrict__ tcp)
{
    __shared__ int csum[256];
    __shared__ int coff[256];
    const int t = threadIdx.x;
    const int base = t * 7;
    int loc[7]; int s = 0;
    #pragma unroll
    for (int i = 0; i < 7; ++i) {
        int g = base + i;
        int v = (g < TBM) ? (vsum[g] > 0.0f ? 1 : 0) : 0;
        loc[i] = v; s += v;
    }
    csum[t] = s;
    __syncthreads();
    if (t == 0) {
        int a = 0;
        for (int i = 0; i < 256; ++i) { coff[i] = a; a += csum[i]; }
        *tcp = a;
    }
    __syncthreads();
    int off = coff[t];
    #pragma unroll
    for (int i = 0; i < 7; ++i) {
        int g = base + i;
        if (g < TBM && loc[i]) cidx[off++] = g;
    }
}

// compact -> t360 fp32 [.][360] and xh f16 [.][384] (pads zero)
__global__ __launch_bounds__(128) void k_compact(
    const float* __restrict__ nodes, const int* __restrict__ cidx,
    const int* __restrict__ tcp, float* __restrict__ xf, _Float16* __restrict__ xh)
{
    const int j = blockIdx.x, b = blockIdx.y;
    const int Tc = *tcp;
    const size_t row = (size_t)b * TBM + j;
    const float* src = (j < Tc) ? nodes + ((size_t)b * TBM + cidx[j]) * EMBD : nullptr;
    for (int e = threadIdx.x; e < 384; e += 128) {
        float v = (e < EMBD && src) ? src[e] : 0.0f;
        if (e < EMBD) xf[row * EMBD + e] = v;
        xh[row * 384 + e] = (_Float16)v;
    }
}

// ---------------------------------------------------------------------------
// Fused split-K reduce + bias + residual + LayerNorm, one WAVE per row.
// ---------------------------------------------------------------------------
__global__ __launch_bounds__(256) void k_lnr(
    const float* __restrict__ p0, const float* __restrict__ p1,
    const float* __restrict__ bias, const float* res,
    const float* __restrict__ sc, const float* __restrict__ bc,
    float* outf, _Float16* __restrict__ outh)
{
    const int lane = threadIdx.x & 63;
    const int row = blockIdx.x * 4 + (threadIdx.x >> 6);
    const size_t ro = (size_t)row * EMBD;
    const int e0 = lane * 6;
    float x[6] = {0.f, 0.f, 0.f, 0.f, 0.f, 0.f};
    float sum = 0.f;
    if (lane < 60) {
        #pragma unroll
        for (int i = 0; i < 6; ++i) {
            float v = p0[ro + e0 + i] + p1[ro + e0 + i] + bias[e0 + i] + res[ro + e0 + i];
            x[i] = v; sum += v;
        }
    }
    #pragma unroll
    for (int o = 32; o >= 1; o >>= 1) sum += __shfl_xor(sum, o);
    const float mean = sum * (1.0f / 360.0f);
    float vs = 0.f;
    if (lane < 60) {
        #pragma unroll
        for (int i = 0; i < 6; ++i) { float d = x[i] - mean; vs += d * d; }
    }
    #pragma unroll
    for (int o = 32; o >= 1; o >>= 1) vs += __shfl_xor(vs, o);
    const float rs = rsqrtf(vs * (1.0f / 360.0f) + 1e-5f);
    _Float16* hrow = outh + (size_t)row * 384;
    if (lane < 60) {
        #pragma unroll
        for (int i = 0; i < 6; ++i) {
            float v = (x[i] - mean) * rs * sc[e0 + i] + bc[e0 + i];
            outf[ro + e0 + i] = v;
            hrow[e0 + i] = (_Float16)v;
        }
    } else {
        #pragma unroll
        for (int i = 0; i < 6; ++i)
            hrow[360 + (lane - 60) * 6 + i] = (_Float16)0.0f;
    }
}

// ---------------------------------------------------------------------------
// Mean stage 1: partial[chunk][b][e] = sum over tokens in chunk.
// ---------------------------------------------------------------------------
__global__ __launch_bounds__(128) void k_mean2(
    const float* __restrict__ x, float* __restrict__ partial,
    const int* __restrict__ tcp)
{
    const int chunk = blockIdx.x;   // 0..15, 108 tokens each
    const int b = blockIdx.y;
    const int t = threadIdx.x;
    const int Tc = *tcp;
    int j0 = chunk * 108;
    int j1 = j0 + 108; if (j1 > Tc) j1 = Tc;
    const float* xb = x + (size_t)b * TBM * EMBD;
    float a0 = 0.f, a1 = 0.f, a2 = 0.f;
    for (int j = j0; j < j1; ++j) {
        const float* r = xb + (size_t)j * EMBD;
        a0 += r[t]; a1 += r[t + 128];
        if (t < 104) a2 += r[t + 256];
    }
    float* p = partial + ((size_t)chunk * NB + b) * EMBD;
    p[t] = a0; p[t + 128] = a1;
    if (t < 104) p[t + 256] = a2;
}

// Head: one block per batch.
__global__ __launch_bounds__(256) void k_head(
    const float* __restrict__ partial, const int* __restrict__ tcp,
    const float* __restrict__ cw1, const float* __restrict__ cb1,
    const float* __restrict__ cw2, const float* __restrict__ cb2,
    const float* __restrict__ cw3, const float* __restrict__ cb3,
    float* __restrict__ outp)
{
    const int b = blockIdx.x;
    __shared__ float hs[EMBD];
    __shared__ float h1[256];
    __shared__ float h2[128];
    const int t = threadIdx.x;
    int Tc = *tcp; if (Tc < 1) Tc = 1;
    const float inv = 1.0f / (float)Tc;
    for (int e = t; e < EMBD; e += 256) {
        float s = 0.f;
        #pragma unroll
        for (int c = 0; c < 16; ++c) s += partial[(size_t)c * NB * EMBD + b * EMBD + e];
        hs[e] = s * inv;
    }
    __syncthreads();
    {
        float s = cb1[t];
        for (int k = 0; k < EMBD; ++k) s = fmaf(hs[k], cw1[k * 256 + t], s);
        h1[t] = gelu_f(s);
    }
    __syncthreads();
    if (t < 128) {
        float s = cb2[t];
        for (int k = 0; k < 256; ++k) s = fmaf(h1[k], cw2[k * 128 + t], s);
        h2[t] = fmaxf(s, 0.0f);
    }
    __syncthreads();
    if (t < 2) {
        float s = cb3[t];
        for (int k = 0; k < 128; ++k) s = fmaf(h2[k], cw3[k * 2 + t], s);
        outp[b * 2 + t] = s;
    }
}

// ---------------------------------------------------------------------------
extern "C" void kernel_launch(void* const* d_in, const int* in_sizes, int n_in,
                              void* d_out, int out_size, void* d_ws, size_t ws_size,
                              hipStream_t stream)
{
    const float* F_roi  = (const float*)d_in[0];
    const int*   C      = (const int*)d_in[1];
    const float* ffn_w1 = (const float*)d_in[2];
    const float* ffn_b1 = (const float*)d_in[3];
    const float* ffn_w2 = (const float*)d_in[4];
    const float* ffn_b2 = (const float*)d_in[5];
    const float* wqkv   = (const float*)d_in[6];
    const float* bqkv   = (const float*)d_in[7];
    const float* wo     = (const float*)d_in[8];
    const float* bo     = (const float*)d_in[9];
    const float* ln1s   = (const float*)d_in[10];
    const float* ln1b   = (const float*)d_in[11];
    const float* wf1    = (const float*)d_in[12];
    const float* bf1    = (const float*)d_in[13];
    const float* wf2    = (const float*)d_in[14];
    const float* bf2    = (const float*)d_in[15];
    const float* ln2s   = (const float*)d_in[16];
    const float* ln2b   = (const float*)d_in[17];
    const float* cw1    = (const float*)d_in[18];
    const float* cb1    = (const float*)d_in[19];
    const float* cw2    = (const float*)d_in[20];
    const float* cb2    = (const float*)d_in[21];
    const float* cw3    = (const float*)d_in[22];
    const float* cb3    = (const float*)d_in[23];
    float* out = (float*)d_out;

    float* ws = (float*)d_ws;
    _Float16* qkvh = (_Float16*)ws;                   // [13824][1152] f16
    float*    tmp450 = ws;                            // alias
    float*    F_emb  = ws + 1440000;                  // alias
    float*    midf   = ws + 7962624;
    _Float16* midb   = (_Float16*)midf;               // [13824][2048] f16
    float*    nodes  = midf;                          // alias fp32
    _Float16* aob    = (_Float16*)(ws + 22118400);    // [13824][384] f16
    float*    p0     = ws + 24772608;
    float*    p1     = ws + 29749248;
    float*    t360   = ws + 34725888;
    _Float16* xh     = (_Float16*)(ws + 39702528);    // [13824][384] f16
    _Float16* sw     = (_Float16*)(ws + 42356736);

    size_t so = 0;
    auto salloc = [&](size_t n) { _Float16* p = sw + so; so += n; return p; };
    _Float16* w1c  = salloc(262144);           // [512][512]
    _Float16* w2c  = salloc(184320);           // [384][480]
    _Float16* qkvc = salloc(2 * 442368);       // [1152][384] x2
    _Float16* woc  = salloc(2 * 147456);       // [384][384]  x2
    _Float16* f1c  = salloc(2 * 786432);       // [2048][384] x2
    _Float16* f2c  = salloc(2 * 786432);       // [384][2048] x2
    float* partial = ws + 44742656;            // 16 x 8 x 360
    int*   ints    = (int*)(partial + 46080);
    int*   cidx    = ints;                     // 1728
    int*   tcp     = ints + 1728;              // 1
    float* vsumf   = (float*)(ints + 1732);    // 1728
    float* bqp     = vsumf + 1728;             // 2 x 1152
    _Float16* vT   = (_Float16*)(ws + 44800000); // [32][96][1728] f16

    dim3 blk(256);

    // Weight conversions
    k_wconv<<<dim3(16, 16, 1), blk, 0, stream>>>(ffn_w1, 512, 450, w1c, 512, 512, 0, 0);
    k_wconv<<<dim3(15, 12, 1), blk, 0, stream>>>(ffn_w2, 450, 360, w2c, 480, 384, 0, 0);
    k_wconv<<<dim3(12, 64, 2), blk, 0, stream>>>(wf1, 360, 2048, f1c, 384, 2048, 360 * 2048, 786432);
    k_wconv<<<dim3(64, 12, 2), blk, 0, stream>>>(wf2, 2048, 360, f2c, 2048, 384, 2048 * 360, 786432);
    k_wmisc<<<dim3(4618), blk, 0, stream>>>(wqkv, wo, bqkv, qkvc, woc, bqp);

    // Node featurization
    hipError_t e0 = hipMemsetAsync(vsumf, 0, TBM * sizeof(float), stream); (void)e0;
    k_mgemm<1, false, false, false, 3><<<dim3(4, 25), blk, 0, stream>>>(F_roi, w1c, ffn_b1, nullptr, tmp450, 3200, 450, 512, 512);
    k_mgemm<0, false, false, false, 3><<<dim3(3, 25), blk, 0, stream>>>(tmp450, w2c, ffn_b2, nullptr, F_emb, 3200, 360, 450, 480);
    k_pool<<<dim3(1728, 8), dim3(128), 0, stream>>>(F_emb, C, nodes, vsumf);
    k_scan<<<dim3(1), blk, 0, stream>>>(vsumf, cidx, tcp);
    k_compact<<<dim3(1728, 8), dim3(128), 0, stream>>>(nodes, cidx, tcp, t360, xh);

    // Transformer layers
    for (int l = 0; l < 2; ++l) {
        k_mgemm<0, false, true, true, 4><<<dim3(9, 108), blk, 0, stream>>>(xh, qkvc + (size_t)l * 442368, bqp + l * 1152, nullptr, qkvh, MTOK, 1152, 360, 384);
        k_vtr<<<dim3(54, 3, 32), blk, 0, stream>>>(qkvh, vT);
        k_mattn<<<dim3(448), blk, 0, stream>>>(qkvh, vT, aob, tcp);
        k_skgemm<<<dim3(3, 108, 2), blk, 0, stream>>>(aob, woc + (size_t)l * 147456, p0, 384, 192, 6);
        k_lnr<<<dim3(MTOK / 4), blk, 0, stream>>>(p0, p1, bo + l * 360, t360, ln1s + l * 360, ln1b + l * 360, t360, xh);
        k_mgemm<1, false, true, true, 4><<<dim3(16, 108), blk, 0, stream>>>(xh, f1c + (size_t)l * 786432, bf1 + l * 2048, nullptr, midb, MTOK, 2048, 360, 384);
        k_skgemm<<<dim3(3, 108, 2), blk, 0, stream>>>(midb, f2c + (size_t)l * 786432, p0, 2048, 1024, 32);
        k_lnr<<<dim3(MTOK / 4), blk, 0, stream>>>(p0, p1, bf2 + l * 360, t360, ln2s + l * 360, ln2b + l * 360, t360, xh);
    }

    // Head
    k_mean2<<<dim3(16, 8), dim3(128), 0, stream>>>(t360, partial, tcp);
    k_head<<<dim3(8), blk, 0, stream>>>(partial, tcp, cw1, cb1, cw2, cb2, cw3, cb3, out);
}

// Round 16
// 623.440 us; speedup vs baseline: 1.1953x; 1.1953x over previous
//
#include <hip/hip_runtime.h>
#include <math.h>

#define NB   8
#define NROI 400
#define GG   25
#define EMBD 360
#define HDD  90
#define TBM  1728
#define MTOK 13824      // NB*TBM

typedef __attribute__((ext_vector_type(8)))  _Float16 h8;   // 8 f16 (4 VGPR)
typedef __attribute__((ext_vector_type(4)))  _Float16 h4;
typedef __attribute__((ext_vector_type(16))) float f32x16;
typedef __attribute__((ext_vector_type(4)))  unsigned u32x4;

#define MFMA16(a,b,c) __builtin_amdgcn_mfma_f32_32x32x16_f16(a,b,c,0,0,0)
#define QSCALE 0.105409255338945984f   /* 1/sqrt(90) */

// direct global->LDS staging, 16B per lane; LDS dest = uniform base + lane*16
#define GLOAD_LDS(G, L) __builtin_amdgcn_global_load_lds( \
    (const __attribute__((address_space(1))) unsigned int*)(G), \
    (__attribute__((address_space(3))) unsigned int*)(L), 16, 0, 0)

__device__ __forceinline__ float gelu_f(float x) {
    return 0.5f * x * (1.0f + erff(x * 0.7071067811865475f));
}

// bijective XCD-aware block remap (m204): logical ids contiguous per XCD.
__device__ __forceinline__ int xcd_swz(int orig, int nwg) {
    int q = nwg >> 3, r = nwg & 7;
    int xcd = orig & 7, loc = orig >> 3;
    int base = (xcd < r) ? xcd * (q + 1) : r * (q + 1) + (xcd - r) * q;
    return base + loc;
}

// ---------------------------------------------------------------------------
// Tiled weight convert+transpose: W[K][N] fp32 -> Wt[Np][Kp] f16 (zero-pad).
// ---------------------------------------------------------------------------
__global__ __launch_bounds__(256) void k_wconv(
    const float* __restrict__ W, int K, int N,
    _Float16* __restrict__ Wt, int Kp, int Np, int Wls, int Wtls)
{
    W  += (size_t)blockIdx.z * Wls;
    Wt += (size_t)blockIdx.z * Wtls;
    __shared__ float tile[32][33];
    const int k0 = blockIdx.x * 32, n0 = blockIdx.y * 32;
    const int t = threadIdx.x;
    #pragma unroll
    for (int it = 0; it < 4; ++it) {
        int e = t + it * 256;
        int i = e >> 5, j = e & 31;
        tile[j][i] = (k0 + i < K && n0 + j < N) ? W[(size_t)(k0 + i) * N + n0 + j] : 0.0f;
    }
    __syncthreads();
    #pragma unroll
    for (int it = 0; it < 4; ++it) {
        int e = t + it * 256;
        int n = e >> 5, kk = e & 31;
        if (n0 + n < Np && k0 + kk < Kp)
            Wt[(size_t)(n0 + n) * Kp + k0 + kk] = (_Float16)tile[n][kk];
    }
}

// qkv(2x) + wo(2x) + qkv-bias(2x) conversions fused into one flat kernel.
__global__ __launch_bounds__(256) void k_wmisc(
    const float* __restrict__ wqkv, const float* __restrict__ wo,
    const float* __restrict__ bqkv,
    _Float16* __restrict__ qkvc, _Float16* __restrict__ woc,
    float* __restrict__ bqp)
{
    int id = blockIdx.x * 256 + threadIdx.x;
    if (id < 884736) {                       // qkv: Wt[1152][384], n' = sec*384+96h+d
        int l = id / 442368, r = id - l * 442368;
        int np = r / 384, kk = r - np * 384;
        int sec = np / 384, rr = np - sec * 384, h = rr / 96, d = rr - h * 96;
        float v = 0.0f;
        if (d < HDD && kk < 360) v = wqkv[(size_t)l * 388800 + (size_t)kk * 1080 + sec * 360 + h * HDD + d];
        if (sec == 0) v *= QSCALE;
        qkvc[id] = (_Float16)v;
    } else if (id < 1179648) {               // wo: Wt[384][384], k' = 96h+d
        int r2 = id - 884736;
        int l = r2 / 147456, r = r2 - l * 147456;
        int n = r / 384, kp = r - n * 384;
        int h = kp / 96, d = kp - h * 96;
        float v = 0.0f;
        if (d < HDD && n < 360) v = wo[(size_t)l * 129600 + (size_t)(h * HDD + d) * 360 + n];
        woc[r2] = (_Float16)v;
    } else if (id < 1181952) {               // padded qkv bias [1152]
        int r3 = id - 1179648;
        int l = r3 / 1152, r = r3 - l * 1152;
        int sec = r / 384, rr = r - sec * 384, h = rr / 96, d = rr - h * 96;
        float v = 0.0f;
        if (d < HDD) v = bqkv[l * 1080 + sec * 360 + h * HDD + d];
        if (sec == 0) v *= QSCALE;
        if (sec == 2 && d == HDD) v = 1.0f;  // softmax denominator column
        bqp[r3] = v;
    }
}

// ---------------------------------------------------------------------------
// V transpose: qkvh V-section [13824][96 per head] -> vT[bh][96][1728] f16.
// ---------------------------------------------------------------------------
__global__ __launch_bounds__(256) void k_vtr(
    const _Float16* __restrict__ qkvh, _Float16* __restrict__ vT)
{
    __shared__ _Float16 tile[32][33];
    const int t = threadIdx.x;
    const int tok0 = blockIdx.x * 32;
    const int d0 = blockIdx.y * 32;
    const int bh = blockIdx.z;              // b*4 + h
    const int b = bh >> 2, h = bh & 3;
    const size_t src = ((size_t)b * TBM + tok0) * 1152 + 768 + 96 * h + d0;
    #pragma unroll
    for (int it = 0; it < 4; ++it) {
        int tl = (t >> 5) + it * 8, dl = t & 31;
        tile[tl][dl] = qkvh[src + (size_t)tl * 1152 + dl];
    }
    __syncthreads();
    const size_t dst = ((size_t)bh * 96 + d0) * TBM + tok0;
    #pragma unroll
    for (int it = 0; it < 4; ++it) {
        int dl = (t >> 5) + it * 8, tl = t & 31;
        vT[dst + (size_t)dl * TBM + tl] = tile[tl][dl];
    }
}

// ---------------------------------------------------------------------------
// MFMA GEMM (f16): C = act(A@B + bias (+res)). 128x128 tile, BK=32, 4 waves.
// AH path: global_load_lds staging into ROW-MAJOR swizzled LDS:
//   slot e = (row = e>>2, x = e&3); chunk stored there = x ^ ((row>>1)&3)
//   (source permuted within the row's 64B -> coalescing preserved).
// Fragment read: &L[(row*4 + (c ^ ((row>>1)&3)))*8] -> 4-deep bank min.
// fp32-A path keeps R14 register-prefetch staging. XCD-swizzled block ids.
// ---------------------------------------------------------------------------
template <int ACT, bool RES, bool OUTH, bool AH, int MW>
__global__ __launch_bounds__(256, MW) void k_mgemm(
    const void* __restrict__ Ap, const _Float16* __restrict__ Bt,
    const float* __restrict__ bias, const float* res, void* Cp,
    int M, int N, int K, int Kp)
{
    __shared__ __align__(16) _Float16 Ah[4096], Bh[4096];
    const int t = threadIdx.x;
    const int lane = t & 63, wid = t >> 6;
    const int half = lane >> 5, l31 = lane & 31;
    const int nwg = gridDim.x * gridDim.y;
    const int logical = xcd_swz(blockIdx.y * gridDim.x + blockIdx.x, nwg);
    const int m0 = (logical / gridDim.x) * 128, n0 = (logical % gridDim.x) * 128;
    const int wm = (wid >> 1) * 64, wn = (wid & 1) * 64;
    const int wb = t & 192;          // wave-uniform slot base within 256

    f32x16 acc00 = {}, acc01 = {}, acc10 = {}, acc11 = {};
    const int nk = Kp >> 5;
    const bool k4 = (K & 3) == 0;

    const _Float16* Af = (const _Float16*)Ap;
    const float* A = (const float*)Ap;

    if (AH) {
        // per-thread staging source offsets (row-major slots, chunk swizzled)
        int soff[2];
        #pragma unroll
        for (int i = 0; i < 2; ++i) {
            int e = t + i * 256;
            int row = e >> 2, x = e & 3;
            int c = x ^ ((row >> 1) & 3);
            soff[i] = row * Kp + c * 8;
        }
        for (int ks = 0; ks < nk; ++ks) {
            const int k0 = ks << 5;
            __syncthreads();   // previous iteration's LDS readers done
            #pragma unroll
            for (int i = 0; i < 2; ++i) {
                GLOAD_LDS(Af + (size_t)m0 * Kp + k0 + soff[i], &Ah[(i * 256 + wb) * 8]);
                GLOAD_LDS(Bt + (size_t)n0 * Kp + k0 + soff[i], &Bh[(i * 256 + wb) * 8]);
            }
            __syncthreads();   // drains vmcnt before use
            h8 af[2][2], bf[2][2];
            #pragma unroll
            for (int m2 = 0; m2 < 2; ++m2)
                #pragma unroll
                for (int ku = 0; ku < 2; ++ku) {
                    int c = ku * 2 + half;
                    int ra = wm + m2 * 32 + l31;
                    int rb = wn + m2 * 32 + l31;
                    af[m2][ku] = *(const h8*)&Ah[(ra * 4 + (c ^ ((ra >> 1) & 3))) * 8];
                    bf[m2][ku] = *(const h8*)&Bh[(rb * 4 + (c ^ ((rb >> 1) & 3))) * 8];
                }
            #pragma unroll
            for (int ku = 0; ku < 2; ++ku) {
                acc00 = MFMA16(af[0][ku], bf[0][ku], acc00);
                acc01 = MFMA16(af[0][ku], bf[1][ku], acc01);
                acc10 = MFMA16(af[1][ku], bf[0][ku], acc10);
                acc11 = MFMA16(af[1][ku], bf[1][ku], acc11);
            }
        }
    } else {
        float4 fcur[4], fnxt[4];
        h8 bcur[2], bnxt[2];
        auto loadA_f = [&](int k0, float4* dst) {
            #pragma unroll
            for (int i = 0; i < 4; ++i) {
                int e = t + i * 256;
                int row = e >> 3, c4 = e & 7;
                int gm = m0 + row, kb = k0 + c4 * 4;
                float4 fv = {0.f, 0.f, 0.f, 0.f};
                if (gm < M) {
                    const float* ap = A + (size_t)gm * K + kb;
                    if (k4 && kb + 3 < K) {
                        fv = *(const float4*)ap;
                    } else {
                        if (kb + 0 < K) fv.x = ap[0];
                        if (kb + 1 < K) fv.y = ap[1];
                        if (kb + 2 < K) fv.z = ap[2];
                        if (kb + 3 < K) fv.w = ap[3];
                    }
                }
                dst[i] = fv;
            }
        };
        auto loadB = [&](int k0, h8* dst) {
            #pragma unroll
            for (int i = 0; i < 2; ++i) {
                int e = t + i * 256;
                int col = e >> 2, c = e & 3;
                dst[i] = *(const h8*)(Bt + (size_t)(n0 + col) * Kp + k0 + c * 8);
            }
        };
        loadA_f(0, fcur); loadB(0, bcur);
        for (int ks = 0; ks < nk; ++ks) {
            const bool pf = (ks + 1 < nk);
            if (pf) { loadA_f((ks + 1) << 5, fnxt); loadB((ks + 1) << 5, bnxt); }
            __syncthreads();
            #pragma unroll
            for (int i = 0; i < 4; ++i) {
                int e = t + i * 256;
                int row = e >> 3, c4 = e & 7;
                float4 fv = fcur[i];
                h4 hv = { (_Float16)fv.x, (_Float16)fv.y, (_Float16)fv.z, (_Float16)fv.w };
                int c = c4 >> 1, sub = c4 & 1;
                *(h4*)&Ah[(c * 128 + row) * 8 + sub * 4] = hv;
            }
            #pragma unroll
            for (int i = 0; i < 2; ++i) {
                int e = t + i * 256;
                int col = e >> 2, c = e & 3;
                *(h8*)&Bh[(c * 128 + col) * 8] = bcur[i];
            }
            __syncthreads();
            h8 af[2][2], bf[2][2];
            #pragma unroll
            for (int m2 = 0; m2 < 2; ++m2)
                #pragma unroll
                for (int ku = 0; ku < 2; ++ku) {
                    int c = ku * 2 + half;
                    af[m2][ku] = *(const h8*)&Ah[(c * 128 + wm + m2 * 32 + l31) * 8];
                    bf[m2][ku] = *(const h8*)&Bh[(c * 128 + wn + m2 * 32 + l31) * 8];
                }
            #pragma unroll
            for (int ku = 0; ku < 2; ++ku) {
                acc00 = MFMA16(af[0][ku], bf[0][ku], acc00);
                acc01 = MFMA16(af[0][ku], bf[1][ku], acc01);
                acc10 = MFMA16(af[1][ku], bf[0][ku], acc10);
                acc11 = MFMA16(af[1][ku], bf[1][ku], acc11);
            }
            if (pf) {
                fcur[0] = fnxt[0]; fcur[1] = fnxt[1]; fcur[2] = fnxt[2]; fcur[3] = fnxt[3];
                bcur[0] = bnxt[0]; bcur[1] = bnxt[1];
            }
        }
    }
    float* Cf = (float*)Cp;
    _Float16* Ch = (_Float16*)Cp;
    #define EPILOG(ACCV, M2, N2) { \
        int gn = n0 + wn + (N2) * 32 + l31; \
        if (gn < N) { \
            float bv = bias[gn]; \
            _Pragma("unroll") \
            for (int r = 0; r < 16; ++r) { \
                int gm = m0 + wm + (M2) * 32 + (r & 3) + 8 * (r >> 2) + 4 * half; \
                if (gm < M) { \
                    float v = ACCV[r] + bv; \
                    if (RES) v += res[(size_t)gm * N + gn]; \
                    if (ACT == 1) v = gelu_f(v); \
                    if (OUTH) Ch[(size_t)gm * N + gn] = (_Float16)v; \
                    else      Cf[(size_t)gm * N + gn] = v; \
                } } } }
    EPILOG(acc00, 0, 0) EPILOG(acc01, 0, 1) EPILOG(acc10, 1, 0) EPILOG(acc11, 1, 1)
    #undef EPILOG
}

// ---------------------------------------------------------------------------
// Split-K GEMM, global_load_lds staging (row-major swizzled LDS), XCD swizzle.
// ---------------------------------------------------------------------------
__global__ __launch_bounds__(256, 4) void k_skgemm(
    const _Float16* __restrict__ A, const _Float16* __restrict__ Bt,
    float* __restrict__ P, int Kp, int KCH, int nstep)
{
    __shared__ __align__(16) _Float16 Ah[4096], Bh[4096];
    const int t = threadIdx.x;
    const int lane = t & 63, wid = t >> 6;
    const int half = lane >> 5, l31 = lane & 31;
    const int nwg = gridDim.x * gridDim.y;
    const int logical = xcd_swz(blockIdx.y * gridDim.x + blockIdx.x, nwg);
    const int m0 = (logical / gridDim.x) * 128, n0 = (logical % gridDim.x) * 128;
    const int wm = (wid >> 1) * 64, wn = (wid & 1) * 64;
    const int zb = blockIdx.z * KCH;
    const int wb = t & 192;
    P += (size_t)blockIdx.z * MTOK * EMBD;

    f32x16 acc00 = {}, acc01 = {}, acc10 = {}, acc11 = {};

    int soff[2];
    #pragma unroll
    for (int i = 0; i < 2; ++i) {
        int e = t + i * 256;
        int row = e >> 2, x = e & 3;
        int c = x ^ ((row >> 1) & 3);
        soff[i] = row * Kp + c * 8;
    }

    for (int ks = 0; ks < nstep; ++ks) {
        const int k0 = zb + (ks << 5);
        __syncthreads();
        #pragma unroll
        for (int i = 0; i < 2; ++i) {
            GLOAD_LDS(A  + (size_t)m0 * Kp + k0 + soff[i], &Ah[(i * 256 + wb) * 8]);
            GLOAD_LDS(Bt + (size_t)n0 * Kp + k0 + soff[i], &Bh[(i * 256 + wb) * 8]);
        }
        __syncthreads();
        h8 af[2][2], bf[2][2];
        #pragma unroll
        for (int m2 = 0; m2 < 2; ++m2)
            #pragma unroll
            for (int ku = 0; ku < 2; ++ku) {
                int c = ku * 2 + half;
                int ra = wm + m2 * 32 + l31;
                int rb = wn + m2 * 32 + l31;
                af[m2][ku] = *(const h8*)&Ah[(ra * 4 + (c ^ ((ra >> 1) & 3))) * 8];
                bf[m2][ku] = *(const h8*)&Bh[(rb * 4 + (c ^ ((rb >> 1) & 3))) * 8];
            }
        #pragma unroll
        for (int ku = 0; ku < 2; ++ku) {
            acc00 = MFMA16(af[0][ku], bf[0][ku], acc00);
            acc01 = MFMA16(af[0][ku], bf[1][ku], acc01);
            acc10 = MFMA16(af[1][ku], bf[0][ku], acc10);
            acc11 = MFMA16(af[1][ku], bf[1][ku], acc11);
        }
    }
    #define EPILOGP(ACCV, M2, N2) { \
        int gn = n0 + wn + (N2) * 32 + l31; \
        if (gn < EMBD) { \
            _Pragma("unroll") \
            for (int r = 0; r < 16; ++r) { \
                int gm = m0 + wm + (M2) * 32 + (r & 3) + 8 * (r >> 2) + 4 * half; \
                P[(size_t)gm * EMBD + gn] = ACCV[r]; \
            } } }
    EPILOGP(acc00, 0, 0) EPILOGP(acc01, 0, 1) EPILOGP(acc10, 1, 0) EPILOGP(acc11, 1, 1)
    #undef EPILOGP
}

// ---------------------------------------------------------------------------
// Flash attention, f16 MFMA (T12 in-register softmax). Unchanged from R12.
// ---------------------------------------------------------------------------
__global__ __launch_bounds__(256, 2) void k_mattn(
    const _Float16* __restrict__ qkv, const _Float16* __restrict__ vT,
    _Float16* __restrict__ aob, const int* __restrict__ tcp)
{
    __shared__ __align__(16) _Float16 Kl[2][8192];   // [buf][kk*128 + chunk^ (kk&7)]
    __shared__ __align__(16) _Float16 Vl[2][6144];   // [buf][d*64 + (m^(d&7))*8]

    const int t = threadIdx.x;
    const int lane = t & 63, wid = t >> 6;
    const int half = lane >> 5, l31 = lane & 31;
    const int bid = blockIdx.x;
    const int bh = bid & 31, qt = bid >> 5;
    const int h = bh & 3, b = bh >> 2;
    const int Tc = *tcp;
    const int q0w = qt * 128 + wid * 32;
    const size_t base = (size_t)b * TBM * 1152 + 96 * h;
    const _Float16* vTb = vT + (size_t)bh * 96 * TBM;

    int skk[3], scc[3], sdd[3], smm[3];
    int koff[3], voff[3];
    #pragma unroll
    for (int i = 0; i < 3; ++i) {
        int cid = t + i * 256;
        skk[i] = cid / 12; scc[i] = cid - skk[i] * 12;
        sdd[i] = cid >> 3; smm[i] = cid & 7;
        koff[i] = skk[i] * 128 + ((scc[i] ^ (skk[i] & 7)) << 3);
        voff[i] = sdd[i] * 64 + ((smm[i] ^ (sdd[i] & 7)) << 3);
    }

    h8 qf[6];
    {
        int rl = q0w + l31; if (rl > TBM - 1) rl = TBM - 1;
        const _Float16* qrow = qkv + base + (size_t)rl * 1152;
        #pragma unroll
        for (int ku = 0; ku < 6; ++ku)
            qf[ku] = *(const h8*)(qrow + ku * 16 + half * 8);
    }

    f32x16 o0 = {}, o1 = {}, o2 = {};
    int nkt = (Tc + 63) >> 6; if (nkt > 27) nkt = 27;

    if (nkt > 0) {
        #pragma unroll
        for (int i = 0; i < 3; ++i) {
            *(h8*)&Kl[0][koff[i]] =
                *(const h8*)(qkv + base + (size_t)skk[i] * 1152 + 384 + scc[i] * 8);
            *(h8*)&Vl[0][voff[i]] =
                *(const h8*)(vTb + (size_t)sdd[i] * TBM + smm[i] * 8);
        }
    }
    __syncthreads();

    for (int kt = 0; kt < nkt; ++kt) {
        const int k0 = kt * 64;
        const int cur = kt & 1, nxt = cur ^ 1;
        h8 kpre[3], vpre[3];
        const bool pf = (kt + 1 < nkt);
        if (pf) {
            #pragma unroll
            for (int i = 0; i < 3; ++i) {
                kpre[i] = *(const h8*)(qkv + base + (size_t)(k0 + 64 + skk[i]) * 1152 + 384 + scc[i] * 8);
                vpre[i] = *(const h8*)(vTb + (size_t)sdd[i] * TBM + k0 + 64 + smm[i] * 8);
            }
        }
        // S^T = K Q (12 MFMAs)
        f32x16 sT0 = {}, sT1 = {};
        #pragma unroll
        for (int ku = 0; ku < 6; ++ku) {
            int c = ku * 2 + half;
            int cp = c ^ (l31 & 7);
            h8 kb0 = *(const h8*)&Kl[cur][l31 * 128 + cp * 8];
            h8 kb1 = *(const h8*)&Kl[cur][(32 + l31) * 128 + cp * 8];
            sT0 = MFMA16(kb0, qf[ku], sT0);
            sT1 = MFMA16(kb1, qf[ku], sT1);
        }
        // exp -> f16 pack -> permlane half-swap -> PV A-fragments (no LDS)
        h8 pa[4];
        #pragma unroll
        for (int g = 0; g < 2; ++g) {
            const f32x16& sT = g ? sT1 : sT0;
            const int kbase = k0 + g * 32;
            unsigned w0, w1, w2, w3, w4, w5, w6, w7;
            #define CVTW(W, R0, R1) { \
                int ka = kbase + ((R0) & 3) + 8 * ((R0) >> 2) + 4 * half; \
                int kb_ = kbase + ((R1) & 3) + 8 * ((R1) >> 2) + 4 * half; \
                float pva = (ka  < Tc) ? __expf(sT[R0]) : 0.0f; \
                float pvb = (kb_ < Tc) ? __expf(sT[R1]) : 0.0f; \
                W = __builtin_bit_cast(unsigned, __builtin_amdgcn_cvt_pkrtz(pva, pvb)); }
            CVTW(w0, 0, 1)  CVTW(w1, 2, 3)  CVTW(w2, 4, 5)  CVTW(w3, 6, 7)
            CVTW(w4, 8, 9)  CVTW(w5, 10, 11) CVTW(w6, 12, 13) CVTW(w7, 14, 15)
            #undef CVTW
            asm volatile("v_permlane32_swap_b32 %0, %1" : "+v"(w0), "+v"(w2));
            asm volatile("v_permlane32_swap_b32 %0, %1" : "+v"(w1), "+v"(w3));
            asm volatile("v_permlane32_swap_b32 %0, %1" : "+v"(w4), "+v"(w6));
            asm volatile("v_permlane32_swap_b32 %0, %1" : "+v"(w5), "+v"(w7));
            u32x4 lo = { w0, w1, w2, w3 };
            u32x4 hi = { w4, w5, w6, w7 };
            pa[g * 2 + 0] = __builtin_bit_cast(h8, lo);
            pa[g * 2 + 1] = __builtin_bit_cast(h8, hi);
        }
        // PV (12 MFMAs)
        #pragma unroll
        for (int n = 0; n < 3; ++n) {
            f32x16* op = n == 0 ? &o0 : (n == 1 ? &o1 : &o2);
            int d = n * 32 + l31;
            #pragma unroll
            for (int ku = 0; ku < 4; ++ku) {
                int m = ku * 2 + half;
                h8 vb = *(const h8*)&Vl[cur][d * 64 + ((m ^ (d & 7)) << 3)];
                *op = MFMA16(pa[ku], vb, *op);
            }
        }
        if (pf) {
            #pragma unroll
            for (int i = 0; i < 3; ++i) {
                *(h8*)&Kl[nxt][koff[i]] = kpre[i];
                *(h8*)&Vl[nxt][voff[i]] = vpre[i];
            }
        }
        __syncthreads();
    }

    #pragma unroll
    for (int r = 0; r < 16; ++r) {
        float den = __shfl(o2[r], (lane & 32) | 26);
        float inv = (den > 0.0f) ? 1.0f / den : 0.0f;
        int qg = q0w + (r & 3) + 8 * (r >> 2) + 4 * half;
        if (qg < Tc) {
            _Float16* orow = aob + ((size_t)b * TBM + qg) * 384 + 96 * h;
            orow[l31]      = (_Float16)(o0[r] * inv);
            orow[32 + l31] = (_Float16)(o1[r] * inv);
            orow[64 + l31] = (64 + l31 < HDD) ? (_Float16)(o2[r] * inv) : (_Float16)0.0f;
        }
    }
}

// ---------------------------------------------------------------------------
// Gather + 3^3 sum-pool + |.| mask accumulation (atomic)
// ---------------------------------------------------------------------------
__global__ __launch_bounds__(128) void k_pool(
    const float* __restrict__ F_emb, const int* __restrict__ C,
    float* __restrict__ nodes, float* __restrict__ vsum)
{
    const int tkn = blockIdx.x, b = blockIdx.y;
    const int oz = tkn % 12, oy = (tkn / 12) % 12, ox = tkn / 144;
    __shared__ int idx[27];
    const int tid = threadIdx.x;
    if (tid < 27) {
        int dx = tid / 9, dy = (tid / 3) % 3, dz = tid % 3;
        idx[tid] = C[(((b * GG) + ox * 2 + dx) * GG + oy * 2 + dy) * GG + oz * 2 + dz];
    }
    __syncthreads();
    float a0 = 0.f, a1 = 0.f, a2 = 0.f;
    for (int n = 0; n < 27; ++n) {
        int c = idx[n];
        if (c == 0) continue;
        const float* src = F_emb + (size_t)(b * NROI + (c - 1)) * EMBD;
        a0 += src[tid]; a1 += src[tid + 128];
        if (tid < 104) a2 += src[tid + 256];
    }
    float* dst = nodes + ((size_t)b * TBM + tkn) * EMBD;
    dst[tid] = a0; dst[tid + 128] = a1;
    if (tid < 104) dst[tid + 256] = a2;
    float s = fabsf(a0) + fabsf(a1) + ((tid < 104) ? fabsf(a2) : 0.0f);
    #pragma unroll
    for (int o = 32; o >= 1; o >>= 1) s += __shfl_xor(s, o);
    __shared__ float red[2];
    if ((tid & 63) == 0) red[tid >> 6] = s;
    __syncthreads();
    if (tid == 0) atomicAdd(&vsum[tkn], red[0] + red[1]);
}

__global__ __launch_bounds__(256) void k_scan(
    const float* __restrict__ vsum, int* __restrict__ cidx, int* __restrict__ tcp)
{
    __shared__ int csum[256];
    __shared__ int coff[256];
    const int t = threadIdx.x;
    const int base = t * 7;
    int loc[7]; int s = 0;
    #pragma unroll
    for (int i = 0; i < 7; ++i) {
        int g = base + i;
        int v = (g < TBM) ? (vsum[g] > 0.0f ? 1 : 0) : 0;
        loc[i] = v; s += v;
    }
    csum[t] = s;
    __syncthreads();
    if (t == 0) {
        int a = 0;
        for (int i = 0; i < 256; ++i) { coff[i] = a; a += csum[i]; }
        *tcp = a;
    }
    __syncthreads();
    int off = coff[t];
    #pragma unroll
    for (int i = 0; i < 7; ++i) {
        int g = base + i;
        if (g < TBM && loc[i]) cidx[off++] = g;
    }
}

// compact -> t360 fp32 [.][360] and xh f16 [.][384] (pads zero)
__global__ __launch_bounds__(128) void k_compact(
    const float* __restrict__ nodes, const int* __restrict__ cidx,
    const int* __restrict__ tcp, float* __restrict__ xf, _Float16* __restrict__ xh)
{
    const int j = blockIdx.x, b = blockIdx.y;
    const int Tc = *tcp;
    const size_t row = (size_t)b * TBM + j;
    const float* src = (j < Tc) ? nodes + ((size_t)b * TBM + cidx[j]) * EMBD : nullptr;
    for (int e = threadIdx.x; e < 384; e += 128) {
        float v = (e < EMBD && src) ? src[e] : 0.0f;
        if (e < EMBD) xf[row * EMBD + e] = v;
        xh[row * 384 + e] = (_Float16)v;
    }
}

// ---------------------------------------------------------------------------
// Fused split-K reduce + bias + residual + LayerNorm, one WAVE per row.
// ---------------------------------------------------------------------------
__global__ __launch_bounds__(256) void k_lnr(
    const float* __restrict__ p0, const float* __restrict__ p1,
    const float* __restrict__ bias, const float* res,
    const float* __restrict__ sc, const float* __restrict__ bc,
    float* outf, _Float16* __restrict__ outh)
{
    const int lane = threadIdx.x & 63;
    const int row = blockIdx.x * 4 + (threadIdx.x >> 6);
    const size_t ro = (size_t)row * EMBD;
    const int e0 = lane * 6;
    float x[6] = {0.f, 0.f, 0.f, 0.f, 0.f, 0.f};
    float sum = 0.f;
    if (lane < 60) {
        #pragma unroll
        for (int i = 0; i < 6; ++i) {
            float v = p0[ro + e0 + i] + p1[ro + e0 + i] + bias[e0 + i] + res[ro + e0 + i];
            x[i] = v; sum += v;
        }
    }
    #pragma unroll
    for (int o = 32; o >= 1; o >>= 1) sum += __shfl_xor(sum, o);
    const float mean = sum * (1.0f / 360.0f);
    float vs = 0.f;
    if (lane < 60) {
        #pragma unroll
        for (int i = 0; i < 6; ++i) { float d = x[i] - mean; vs += d * d; }
    }
    #pragma unroll
    for (int o = 32; o >= 1; o >>= 1) vs += __shfl_xor(vs, o);
    const float rs = rsqrtf(vs * (1.0f / 360.0f) + 1e-5f);
    _Float16* hrow = outh + (size_t)row * 384;
    if (lane < 60) {
        #pragma unroll
        for (int i = 0; i < 6; ++i) {
            float v = (x[i] - mean) * rs * sc[e0 + i] + bc[e0 + i];
            outf[ro + e0 + i] = v;
            hrow[e0 + i] = (_Float16)v;
        }
    } else {
        #pragma unroll
        for (int i = 0; i < 6; ++i)
            hrow[360 + (lane - 60) * 6 + i] = (_Float16)0.0f;
    }
}

// ---------------------------------------------------------------------------
// Mean stage 1: partial[chunk][b][e] = sum over tokens in chunk.
// ---------------------------------------------------------------------------
__global__ __launch_bounds__(128) void k_mean2(
    const float* __restrict__ x, float* __restrict__ partial,
    const int* __restrict__ tcp)
{
    const int chunk = blockIdx.x;   // 0..15, 108 tokens each
    const int b = blockIdx.y;
    const int t = threadIdx.x;
    const int Tc = *tcp;
    int j0 = chunk * 108;
    int j1 = j0 + 108; if (j1 > Tc) j1 = Tc;
    const float* xb = x + (size_t)b * TBM * EMBD;
    float a0 = 0.f, a1 = 0.f, a2 = 0.f;
    for (int j = j0; j < j1; ++j) {
        const float* r = xb + (size_t)j * EMBD;
        a0 += r[t]; a1 += r[t + 128];
        if (t < 104) a2 += r[t + 256];
    }
    float* p = partial + ((size_t)chunk * NB + b) * EMBD;
    p[t] = a0; p[t + 128] = a1;
    if (t < 104) p[t + 256] = a2;
}

// Head: one block per batch.
__global__ __launch_bounds__(256) void k_head(
    const float* __restrict__ partial, const int* __restrict__ tcp,
    const float* __restrict__ cw1, const float* __restrict__ cb1,
    const float* __restrict__ cw2, const float* __restrict__ cb2,
    const float* __restrict__ cw3, const float* __restrict__ cb3,
    float* __restrict__ outp)
{
    const int b = blockIdx.x;
    __shared__ float hs[EMBD];
    __shared__ float h1[256];
    __shared__ float h2[128];
    const int t = threadIdx.x;
    int Tc = *tcp; if (Tc < 1) Tc = 1;
    const float inv = 1.0f / (float)Tc;
    for (int e = t; e < EMBD; e += 256) {
        float s = 0.f;
        #pragma unroll
        for (int c = 0; c < 16; ++c) s += partial[(size_t)c * NB * EMBD + b * EMBD + e];
        hs[e] = s * inv;
    }
    __syncthreads();
    {
        float s = cb1[t];
        for (int k = 0; k < EMBD; ++k) s = fmaf(hs[k], cw1[k * 256 + t], s);
        h1[t] = gelu_f(s);
    }
    __syncthreads();
    if (t < 128) {
        float s = cb2[t];
        for (int k = 0; k < 256; ++k) s = fmaf(h1[k], cw2[k * 128 + t], s);
        h2[t] = fmaxf(s, 0.0f);
    }
    __syncthreads();
    if (t < 2) {
        float s = cb3[t];
        for (int k = 0; k < 128; ++k) s = fmaf(h2[k], cw3[k * 2 + t], s);
        outp[b * 2 + t] = s;
    }
}

// ---------------------------------------------------------------------------
extern "C" void kernel_launch(void* const* d_in, const int* in_sizes, int n_in,
                              void* d_out, int out_size, void* d_ws, size_t ws_size,
                              hipStream_t stream)
{
    const float* F_roi  = (const float*)d_in[0];
    const int*   C      = (const int*)d_in[1];
    const float* ffn_w1 = (const float*)d_in[2];
    const float* ffn_b1 = (const float*)d_in[3];
    const float* ffn_w2 = (const float*)d_in[4];
    const float* ffn_b2 = (const float*)d_in[5];
    const float* wqkv   = (const float*)d_in[6];
    const float* bqkv   = (const float*)d_in[7];
    const float* wo     = (const float*)d_in[8];
    const float* bo     = (const float*)d_in[9];
    const float* ln1s   = (const float*)d_in[10];
    const float* ln1b   = (const float*)d_in[11];
    const float* wf1    = (const float*)d_in[12];
    const float* bf1    = (const float*)d_in[13];
    const float* wf2    = (const float*)d_in[14];
    const float* bf2    = (const float*)d_in[15];
    const float* ln2s   = (const float*)d_in[16];
    const float* ln2b   = (const float*)d_in[17];
    const float* cw1    = (const float*)d_in[18];
    const float* cb1    = (const float*)d_in[19];
    const float* cw2    = (const float*)d_in[20];
    const float* cb2    = (const float*)d_in[21];
    const float* cw3    = (const float*)d_in[22];
    const float* cb3    = (const float*)d_in[23];
    float* out = (float*)d_out;

    float* ws = (float*)d_ws;
    _Float16* qkvh = (_Float16*)ws;                   // [13824][1152] f16
    float*    tmp450 = ws;                            // alias
    float*    F_emb  = ws + 1440000;                  // alias
    float*    midf   = ws + 7962624;
    _Float16* midb   = (_Float16*)midf;               // [13824][2048] f16
    float*    nodes  = midf;                          // alias fp32
    _Float16* aob    = (_Float16*)(ws + 22118400);    // [13824][384] f16
    float*    p0     = ws + 24772608;
    float*    p1     = ws + 29749248;
    float*    t360   = ws + 34725888;
    _Float16* xh     = (_Float16*)(ws + 39702528);    // [13824][384] f16
    _Float16* sw     = (_Float16*)(ws + 42356736);

    size_t so = 0;
    auto salloc = [&](size_t n) { _Float16* p = sw + so; so += n; return p; };
    _Float16* w1c  = salloc(262144);           // [512][512]
    _Float16* w2c  = salloc(184320);           // [384][480]
    _Float16* qkvc = salloc(2 * 442368);       // [1152][384] x2
    _Float16* woc  = salloc(2 * 147456);       // [384][384]  x2
    _Float16* f1c  = salloc(2 * 786432);       // [2048][384] x2
    _Float16* f2c  = salloc(2 * 786432);       // [384][2048] x2
    float* partial = ws + 44742656;            // 16 x 8 x 360
    int*   ints    = (int*)(partial + 46080);
    int*   cidx    = ints;                     // 1728
    int*   tcp     = ints + 1728;              // 1
    float* vsumf   = (float*)(ints + 1732);    // 1728
    float* bqp     = vsumf + 1728;             // 2 x 1152
    _Float16* vT   = (_Float16*)(ws + 44800000); // [32][96][1728] f16

    dim3 blk(256);

    // Weight conversions
    k_wconv<<<dim3(16, 16, 1), blk, 0, stream>>>(ffn_w1, 512, 450, w1c, 512, 512, 0, 0);
    k_wconv<<<dim3(15, 12, 1), blk, 0, stream>>>(ffn_w2, 450, 360, w2c, 480, 384, 0, 0);
    k_wconv<<<dim3(12, 64, 2), blk, 0, stream>>>(wf1, 360, 2048, f1c, 384, 2048, 360 * 2048, 786432);
    k_wconv<<<dim3(64, 12, 2), blk, 0, stream>>>(wf2, 2048, 360, f2c, 2048, 384, 2048 * 360, 786432);
    k_wmisc<<<dim3(4618), blk, 0, stream>>>(wqkv, wo, bqkv, qkvc, woc, bqp);

    // Node featurization
    hipError_t e0 = hipMemsetAsync(vsumf, 0, TBM * sizeof(float), stream); (void)e0;
    k_mgemm<1, false, false, false, 3><<<dim3(4, 25), blk, 0, stream>>>(F_roi, w1c, ffn_b1, nullptr, tmp450, 3200, 450, 512, 512);
    k_mgemm<0, false, false, false, 3><<<dim3(3, 25), blk, 0, stream>>>(tmp450, w2c, ffn_b2, nullptr, F_emb, 3200, 360, 450, 480);
    k_pool<<<dim3(1728, 8), dim3(128), 0, stream>>>(F_emb, C, nodes, vsumf);
    k_scan<<<dim3(1), blk, 0, stream>>>(vsumf, cidx, tcp);
    k_compact<<<dim3(1728, 8), dim3(128), 0, stream>>>(nodes, cidx, tcp, t360, xh);

    // Transformer layers
    for (int l = 0; l < 2; ++l) {
        k_mgemm<0, false, true, true, 4><<<dim3(9, 108), blk, 0, stream>>>(xh, qkvc + (size_t)l * 442368, bqp + l * 1152, nullptr, qkvh, MTOK, 1152, 360, 384);
        k_vtr<<<dim3(54, 3, 32), blk, 0, stream>>>(qkvh, vT);
        k_mattn<<<dim3(448), blk, 0, stream>>>(qkvh, vT, aob, tcp);
        k_skgemm<<<dim3(3, 108, 2), blk, 0, stream>>>(aob, woc + (size_t)l * 147456, p0, 384, 192, 6);
        k_lnr<<<dim3(MTOK / 4), blk, 0, stream>>>(p0, p1, bo + l * 360, t360, ln1s + l * 360, ln1b + l * 360, t360, xh);
        k_mgemm<1, false, true, true, 4><<<dim3(16, 108), blk, 0, stream>>>(xh, f1c + (size_t)l * 786432, bf1 + l * 2048, nullptr, midb, MTOK, 2048, 360, 384);
        k_skgemm<<<dim3(3, 108, 2), blk, 0, stream>>>(midb, f2c + (size_t)l * 786432, p0, 2048, 1024, 32);
        k_lnr<<<dim3(MTOK / 4), blk, 0, stream>>>(p0, p1, bf2 + l * 360, t360, ln2s + l * 360, ln2b + l * 360, t360, xh);
    }

    // Head
    k_mean2<<<dim3(16, 8), dim3(128), 0, stream>>>(t360, partial, tcp);
    k_head<<<dim3(8), blk, 0, stream>>>(partial, tcp, cw1, cb1, cw2, cb2, cw3, cb3, out);
}